// Round 1
// baseline (140.222 us; speedup 1.0000x reference)
//
#include <hip/hip_runtime.h>
#include <math.h>

#define BATCH 4
#define NPTS 4096
#define CH 256
#define LN_EPS 1e-6f

// ---------------------------------------------------------------------------
// K0: Wc = Wv @ Wo  (row-major [k][j]),  bc = bv @ Wo + bo
// Grid: 257 blocks x 256 threads. Blocks 0..255 compute one row of Wc each;
// block 256 computes bc.
// ---------------------------------------------------------------------------
__global__ __launch_bounds__(256) void fuse_weights(
    const float* __restrict__ Wv, const float* __restrict__ bv,
    const float* __restrict__ Wo, const float* __restrict__ bo,
    float* __restrict__ Wc, float* __restrict__ bc) {
    const int j = threadIdx.x;
    const int i = blockIdx.x;
    if (i < CH) {
        float acc = 0.f;
        #pragma unroll 4
        for (int c = 0; c < CH; c += 4) {
            const float4 wv = *(const float4*)&Wv[i * CH + c];
            acc = fmaf(wv.x, Wo[(c + 0) * CH + j], acc);
            acc = fmaf(wv.y, Wo[(c + 1) * CH + j], acc);
            acc = fmaf(wv.z, Wo[(c + 2) * CH + j], acc);
            acc = fmaf(wv.w, Wo[(c + 3) * CH + j], acc);
        }
        Wc[i * CH + j] = acc;
    } else {
        float acc = bo[j];
        #pragma unroll 4
        for (int c = 0; c < CH; c += 4) {
            const float4 bv4 = *(const float4*)&bv[c];
            acc = fmaf(bv4.x, Wo[(c + 0) * CH + j], acc);
            acc = fmaf(bv4.y, Wo[(c + 1) * CH + j], acc);
            acc = fmaf(bv4.z, Wo[(c + 2) * CH + j], acc);
            acc = fmaf(bv4.w, Wo[(c + 3) * CH + j], acc);
        }
        bc[j] = acc;
    }
}

// ---------------------------------------------------------------------------
// K1: u[m][n] = sum_k A[m][k] * Wc[k][n] + bc[n]
//     A = inputs flattened [M=16384][K=256], Wc [256][256], u [16384][256]
// Tiling: TM=64 x TN=64 per block, BK=32 k-chunks, 256 threads, 4x4 acc/thread.
// ---------------------------------------------------------------------------
#define TM 64
#define TN 64
#define BK 32

__global__ __launch_bounds__(256) void gemm_u(
    const float* __restrict__ A, const float* __restrict__ Wc,
    const float* __restrict__ bc, float* __restrict__ u) {
    __shared__ float As[BK * TM];  // As[k][m]  (A transposed in LDS)
    __shared__ float Bs[BK * TN];  // Bs[k][n]

    const int tid = threadIdx.x;
    const int m0 = blockIdx.x * TM;
    const int n0 = blockIdx.y * TN;
    const int tx = tid & 15;   // n sub-tile
    const int ty = tid >> 4;   // m sub-tile

    // A load map: 4 threads per row, 8 floats (2x float4) each
    const int arow = tid >> 2;          // 0..63
    const int akq  = (tid & 3) * 8;     // 0,8,16,24
    // B load map: 8 threads per row, 8 floats each
    const int brow = tid >> 3;          // 0..31
    const int bq   = (tid & 7) * 8;     // 0..56

    float acc[4][4] = {{0.f}};

    for (int kc = 0; kc < CH; kc += BK) {
        const float4 a0 = *(const float4*)&A[(size_t)(m0 + arow) * CH + kc + akq];
        const float4 a1 = *(const float4*)&A[(size_t)(m0 + arow) * CH + kc + akq + 4];
        const float4 b0 = *(const float4*)&Wc[(size_t)(kc + brow) * CH + n0 + bq];
        const float4 b1 = *(const float4*)&Wc[(size_t)(kc + brow) * CH + n0 + bq + 4];

        __syncthreads();  // previous iteration's compute must finish before overwrite
        As[(akq + 0) * TM + arow] = a0.x;
        As[(akq + 1) * TM + arow] = a0.y;
        As[(akq + 2) * TM + arow] = a0.z;
        As[(akq + 3) * TM + arow] = a0.w;
        As[(akq + 4) * TM + arow] = a1.x;
        As[(akq + 5) * TM + arow] = a1.y;
        As[(akq + 6) * TM + arow] = a1.z;
        As[(akq + 7) * TM + arow] = a1.w;
        *(float4*)&Bs[brow * TN + bq] = b0;
        *(float4*)&Bs[brow * TN + bq + 4] = b1;
        __syncthreads();

        #pragma unroll
        for (int k = 0; k < BK; ++k) {
            const float4 av = *(const float4*)&As[k * TM + ty * 4];
            const float4 bv4 = *(const float4*)&Bs[k * TN + tx * 4];
            const float am[4] = {av.x, av.y, av.z, av.w};
            const float bn[4] = {bv4.x, bv4.y, bv4.z, bv4.w};
            #pragma unroll
            for (int i = 0; i < 4; ++i)
                #pragma unroll
                for (int jj = 0; jj < 4; ++jj)
                    acc[i][jj] = fmaf(am[i], bn[jj], acc[i][jj]);
        }
    }

    const float4 bcv = *(const float4*)&bc[n0 + tx * 4];
    #pragma unroll
    for (int i = 0; i < 4; ++i) {
        float4 r;
        r.x = acc[i][0] + bcv.x;
        r.y = acc[i][1] + bcv.y;
        r.z = acc[i][2] + bcv.z;
        r.w = acc[i][3] + bcv.w;
        *(float4*)&u[(size_t)(m0 + ty * 4 + i) * CH + n0 + tx * 4] = r;
    }
}

// ---------------------------------------------------------------------------
// K2: per-(b,c) partial sums of u and u^2 over 64-row slices, fp32 atomics.
//     acc layout: [0 .. B*CH) = sum, [B*CH .. 2*B*CH) = sumsq
// ---------------------------------------------------------------------------
__global__ __launch_bounds__(256) void ln_stats(
    const float* __restrict__ u, float* __restrict__ acc) {
    const int b = blockIdx.x;    // 0..3
    const int sl = blockIdx.y;   // 0..63
    const int c = threadIdx.x;   // 0..255
    const float* base = u + ((size_t)b * NPTS + (size_t)sl * 64) * CH + c;
    float s1 = 0.f, s2 = 0.f;
    #pragma unroll 8
    for (int n = 0; n < 64; ++n) {
        const float x = base[(size_t)n * CH];
        s1 += x;
        s2 = fmaf(x, x, s2);
    }
    atomicAdd(&acc[b * CH + c], s1);
    atomicAdd(&acc[BATCH * CH + b * CH + c], s2);
}

// ---------------------------------------------------------------------------
// K3: out = relu((u - mean) * rsqrt(var+eps) * scale + bias) + inputs
//     One thread per 4 consecutive channels (float4).
// ---------------------------------------------------------------------------
__global__ __launch_bounds__(256) void ln_finish(
    const float* __restrict__ u, const float* __restrict__ inp,
    const float* __restrict__ acc, const float* __restrict__ scale,
    const float* __restrict__ bias, float* __restrict__ out) {
    const int idx = blockIdx.x * blockDim.x + threadIdx.x;  // 0 .. B*N*C/4
    const int c4 = (idx & 63) * 4;   // channel group
    const int bn = idx >> 6;         // 0..16383
    const int b = bn >> 12;          // 4096 points per batch
    const size_t off = (size_t)idx * 4;

    const float4 uv = *(const float4*)&u[off];
    const float4 xv = *(const float4*)&inp[off];
    const float4 s1 = *(const float4*)&acc[b * CH + c4];
    const float4 s2 = *(const float4*)&acc[BATCH * CH + b * CH + c4];
    const float4 sc = *(const float4*)&scale[c4];
    const float4 bi = *(const float4*)&bias[c4];

    const float invN = 1.f / (float)NPTS;
    float uu[4] = {uv.x, uv.y, uv.z, uv.w};
    float xx[4] = {xv.x, xv.y, xv.z, xv.w};
    float a1[4] = {s1.x, s1.y, s1.z, s1.w};
    float a2[4] = {s2.x, s2.y, s2.z, s2.w};
    float scv[4] = {sc.x, sc.y, sc.z, sc.w};
    float biv[4] = {bi.x, bi.y, bi.z, bi.w};
    float r[4];
    #pragma unroll
    for (int j = 0; j < 4; ++j) {
        const float mean = a1[j] * invN;
        const float var = a2[j] * invN - mean * mean;
        const float inv = rsqrtf(var + LN_EPS);
        float y = (uu[j] - mean) * inv * scv[j] + biv[j];
        y = fmaxf(y, 0.f) + xx[j];
        r[j] = y;
    }
    float4 ro;
    ro.x = r[0]; ro.y = r[1]; ro.z = r[2]; ro.w = r[3];
    *(float4*)&out[off] = ro;
}

// ---------------------------------------------------------------------------
extern "C" void kernel_launch(void* const* d_in, const int* in_sizes, int n_in,
                              void* d_out, int out_size, void* d_ws, size_t ws_size,
                              hipStream_t stream) {
    const float* inputs   = (const float*)d_in[0];
    // d_in[1] = mask (unused: renormalized attention column-sum == 1 to 1e-9)
    // d_in[2..5] = Wq,bq,Wk,bk (unused for the same reason)
    const float* Wv       = (const float*)d_in[6];
    const float* bv       = (const float*)d_in[7];
    const float* Wo       = (const float*)d_in[8];
    const float* bo       = (const float*)d_in[9];
    const float* ln_scale = (const float*)d_in[10];
    const float* ln_bias  = (const float*)d_in[11];
    float* out = (float*)d_out;

    float* Wc  = (float*)d_ws;                       // 256*256
    float* bc  = Wc + CH * CH;                       // 256
    float* u   = bc + CH;                            // B*N*C
    float* acc = u + (size_t)BATCH * NPTS * CH;      // 2*B*CH

    hipMemsetAsync(acc, 0, 2 * BATCH * CH * sizeof(float), stream);
    fuse_weights<<<257, 256, 0, stream>>>(Wv, bv, Wo, bo, Wc, bc);
    gemm_u<<<dim3((BATCH * NPTS) / TM, CH / TN), 256, 0, stream>>>(inputs, Wc, bc, u);
    ln_stats<<<dim3(BATCH, 64), 256, 0, stream>>>(u, acc);
    ln_finish<<<(BATCH * NPTS * CH / 4) / 256, 256, 0, stream>>>(
        u, inputs, acc, ln_scale, ln_bias, out);
}

// Round 2
// 121.617 us; speedup vs baseline: 1.1530x; 1.1530x over previous
//
#include <hip/hip_runtime.h>
#include <math.h>

#define BATCH 4
#define NPTS 4096
#define CH 256
#define LN_EPS 1e-6f

typedef __attribute__((ext_vector_type(8))) _Float16 half8;
typedef __attribute__((ext_vector_type(4))) float f32x4;

// ---------------------------------------------------------------------------
// K0: Wct[n][k] = fp16( (Wv @ Wo)[k][n] )   (transposed, fp16, for MFMA B-frags)
//     bc = bv @ Wo + bo (fp32). Block 256 also zero-inits the stats buffer.
// ---------------------------------------------------------------------------
__global__ __launch_bounds__(256) void fuse_weights(
    const float* __restrict__ Wv, const float* __restrict__ bv,
    const float* __restrict__ Wo, const float* __restrict__ bo,
    _Float16* __restrict__ Wct, float* __restrict__ bc,
    float* __restrict__ accg) {
    const int j = threadIdx.x;
    const int i = blockIdx.x;
    if (i < CH) {
        float acc = 0.f;
        #pragma unroll 4
        for (int c = 0; c < CH; c += 4) {
            const float4 wv = *(const float4*)&Wv[i * CH + c];
            acc = fmaf(wv.x, Wo[(c + 0) * CH + j], acc);
            acc = fmaf(wv.y, Wo[(c + 1) * CH + j], acc);
            acc = fmaf(wv.z, Wo[(c + 2) * CH + j], acc);
            acc = fmaf(wv.w, Wo[(c + 3) * CH + j], acc);
        }
        Wct[(size_t)j * CH + i] = (_Float16)acc;  // transposed store
    } else {
        float acc = bo[j];
        #pragma unroll 4
        for (int c = 0; c < CH; c += 4) {
            const float4 bv4 = *(const float4*)&bv[c];
            acc = fmaf(bv4.x, Wo[(c + 0) * CH + j], acc);
            acc = fmaf(bv4.y, Wo[(c + 1) * CH + j], acc);
            acc = fmaf(bv4.z, Wo[(c + 2) * CH + j], acc);
            acc = fmaf(bv4.w, Wo[(c + 3) * CH + j], acc);
        }
        bc[j] = acc;
        // zero the stats buffer (2*BATCH*CH floats), replaces hipMemsetAsync
        #pragma unroll
        for (int t = 0; t < 2 * BATCH; ++t)
            accg[t * CH + j] = 0.f;
    }
}

// ---------------------------------------------------------------------------
// K1: u = fp16-MFMA( inputs @ Wc ) + bc, with fused LN stats (sum, sumsq per
//     (batch, channel)) via wave shuffle-reduce + global fp32 atomics.
// Block tile 64(M)x64(N), 4 waves; wave w computes rows [w*16,w*16+16) x 64 n
// as 4 frags of mfma_f32_16x16x32_f16. B panel (64n x 256k fp16) in LDS once.
// ---------------------------------------------------------------------------
#define APAD 40   // 32 + 8 fp16 pad -> 80B row stride, 2-way bank alias (free)
#define BPAD 264  // 256 + 8 fp16 pad -> 528B row stride

__global__ __launch_bounds__(256) void gemm_fused(
    const float* __restrict__ A, const _Float16* __restrict__ Wct,
    const float* __restrict__ bc, float* __restrict__ u,
    float* __restrict__ accg) {
    __shared__ _Float16 Bst[64][BPAD];  // [n_local][k]
    __shared__ _Float16 As[64][APAD];   // [m_local][k_chunk]

    const int tid = threadIdx.x;
    const int m0 = blockIdx.x * 64;
    const int n0 = blockIdx.y * 64;
    const int w = tid >> 6;      // wave 0..3
    const int l = tid & 63;
    const int lr = l & 15;
    const int lq = l >> 4;

    // ---- load B panel once: rows n0..n0+63 of Wct, 256 fp16 each ----
    {
        const int nr = tid >> 2;             // 0..63
        const int ks = (tid & 3) * 64;       // 0,64,128,192
        #pragma unroll
        for (int i = 0; i < 8; ++i) {
            half8 v = *(const half8*)&Wct[(size_t)(n0 + nr) * CH + ks + i * 8];
            *(half8*)&Bst[nr][ks + i * 8] = v;
        }
    }

    f32x4 acc[4];
    #pragma unroll
    for (int f = 0; f < 4; ++f) acc[f] = (f32x4){0.f, 0.f, 0.f, 0.f};

    const int arow = tid >> 2;          // m_local 0..63
    const int akseg = (tid & 3) * 8;    // 0,8,16,24

    for (int kc = 0; kc < CH; kc += 32) {
        const float* aptr = &A[(size_t)(m0 + arow) * CH + kc + akseg];
        const float4 a0 = *(const float4*)aptr;
        const float4 a1 = *(const float4*)(aptr + 4);
        half8 ah;
        ah[0] = (_Float16)a0.x; ah[1] = (_Float16)a0.y;
        ah[2] = (_Float16)a0.z; ah[3] = (_Float16)a0.w;
        ah[4] = (_Float16)a1.x; ah[5] = (_Float16)a1.y;
        ah[6] = (_Float16)a1.z; ah[7] = (_Float16)a1.w;

        __syncthreads();  // prior iteration's frag reads done before overwrite
        *(half8*)&As[arow][akseg] = ah;
        __syncthreads();

        const half8 afrag = *(const half8*)&As[w * 16 + lr][lq * 8];
        #pragma unroll
        for (int f = 0; f < 4; ++f) {
            const half8 bfrag = *(const half8*)&Bst[f * 16 + lr][kc + lq * 8];
            acc[f] = __builtin_amdgcn_mfma_f32_16x16x32_f16(afrag, bfrag, acc[f], 0, 0, 0);
        }
    }

    // ---- epilogue: add bc, store u, fused LN stats ----
    const int batch = m0 >> 12;  // 4096 rows per batch; 64-row tile never crosses
    const int mbase = m0 + w * 16 + lq * 4;
    #pragma unroll
    for (int f = 0; f < 4; ++f) {
        const int n = n0 + f * 16 + lr;
        const float bcn = bc[n];
        float s1 = 0.f, s2 = 0.f;
        #pragma unroll
        for (int r = 0; r < 4; ++r) {
            const float v = acc[f][r] + bcn;   // C/D: col=lane&15, row=lq*4+r
            u[(size_t)(mbase + r) * CH + n] = v;
            s1 += v;
            s2 = fmaf(v, v, s2);
        }
        s1 += __shfl_xor(s1, 16, 64);
        s1 += __shfl_xor(s1, 32, 64);
        s2 += __shfl_xor(s2, 16, 64);
        s2 += __shfl_xor(s2, 32, 64);
        if (lq == 0) {
            atomicAdd(&accg[batch * CH + n], s1);
            atomicAdd(&accg[BATCH * CH + batch * CH + n], s2);
        }
    }
}

// ---------------------------------------------------------------------------
// K2: out = relu((u - mean) * rsqrt(var+eps) * scale + bias) + inputs
// ---------------------------------------------------------------------------
__global__ __launch_bounds__(256) void ln_finish(
    const float* __restrict__ u, const float* __restrict__ inp,
    const float* __restrict__ accg, const float* __restrict__ scale,
    const float* __restrict__ bias, float* __restrict__ out) {
    const int idx = blockIdx.x * blockDim.x + threadIdx.x;  // 0 .. B*N*C/4
    const int c4 = (idx & 63) * 4;   // channel group
    const int bn = idx >> 6;         // point index 0..16383
    const int b = bn >> 12;
    const size_t off = (size_t)idx * 4;

    const float4 uv = *(const float4*)&u[off];
    const float4 xv = *(const float4*)&inp[off];
    const float4 s1 = *(const float4*)&accg[b * CH + c4];
    const float4 s2 = *(const float4*)&accg[BATCH * CH + b * CH + c4];
    const float4 sc = *(const float4*)&scale[c4];
    const float4 bi = *(const float4*)&bias[c4];

    const float invN = 1.f / (float)NPTS;
    float uu[4] = {uv.x, uv.y, uv.z, uv.w};
    float xx[4] = {xv.x, xv.y, xv.z, xv.w};
    float a1[4] = {s1.x, s1.y, s1.z, s1.w};
    float a2[4] = {s2.x, s2.y, s2.z, s2.w};
    float scv[4] = {sc.x, sc.y, sc.z, sc.w};
    float biv[4] = {bi.x, bi.y, bi.z, bi.w};
    float r[4];
    #pragma unroll
    for (int j = 0; j < 4; ++j) {
        const float mean = a1[j] * invN;
        const float var = a2[j] * invN - mean * mean;
        const float inv = rsqrtf(var + LN_EPS);
        float y = (uu[j] - mean) * inv * scv[j] + biv[j];
        r[j] = fmaxf(y, 0.f) + xx[j];
    }
    float4 ro;
    ro.x = r[0]; ro.y = r[1]; ro.z = r[2]; ro.w = r[3];
    *(float4*)&out[off] = ro;
}

// ---------------------------------------------------------------------------
extern "C" void kernel_launch(void* const* d_in, const int* in_sizes, int n_in,
                              void* d_out, int out_size, void* d_ws, size_t ws_size,
                              hipStream_t stream) {
    const float* inputs   = (const float*)d_in[0];
    // d_in[1..5] = mask, Wq, bq, Wk, bk — unused: the renormalized attention
    // column-sum equals 1 to within 1e-9 for any mask/logits realization.
    const float* Wv       = (const float*)d_in[6];
    const float* bv       = (const float*)d_in[7];
    const float* Wo       = (const float*)d_in[8];
    const float* bo       = (const float*)d_in[9];
    const float* ln_scale = (const float*)d_in[10];
    const float* ln_bias  = (const float*)d_in[11];
    float* out = (float*)d_out;

    // workspace layout (16B-aligned slices)
    float*     u    = (float*)d_ws;                              // B*N*C fp32
    float*     accg = (float*)((char*)d_ws + (size_t)BATCH * NPTS * CH * 4);  // 2*B*C
    _Float16*  Wct  = (_Float16*)((char*)accg + 2 * BATCH * CH * 4);          // C*C fp16
    float*     bc   = (float*)((char*)Wct + (size_t)CH * CH * 2);             // C

    fuse_weights<<<CH + 1, 256, 0, stream>>>(Wv, bv, Wo, bo, Wct, bc, accg);
    gemm_fused<<<dim3((BATCH * NPTS) / 64, CH / 64), 256, 0, stream>>>(
        inputs, Wct, bc, u, accg);
    ln_finish<<<(BATCH * NPTS * CH / 4) / 256, 256, 0, stream>>>(
        u, inputs, accg, ln_scale, ln_bias, out);
}